// Round 1
// baseline (381.227 us; speedup 1.0000x reference)
//
#include <hip/hip_runtime.h>

typedef unsigned short ushort_t;
typedef unsigned int uint_t;
typedef __bf16 bf16x8 __attribute__((ext_vector_type(8)));
typedef float f32x4 __attribute__((ext_vector_type(4)));

#define B_ROWS 65536

// Tile geometry: one MFMA tile = 16 rows x 32 k of bf16 = 1024 B = 512 ushorts.
// Unit l (0..63) within a tile <-> (row = l&15, k = (l>>4)*8 .. +8).
#define KT1 12    // x' k-tiles   (K 376 -> 384)
#define NT1 30    // K1 n-tiles   (N 400 -> 480)
#define KTC1 15   // h1' k-tiles  (480/32)
#define KI2 13    // K2 k-iters   (K 400 -> 416)
#define NT2 20    // K2 n-tiles   (N 320)
#define KTC2 10   // h2' k-tiles  (320/32)
#define KI3 10    // K3 k-iters   (320/32)
#define NT3 40    // K3 n-tiles   (N 560 -> 640)
#define LDH3 20   // heads' row-stride in ktiles (640/32)

#define SZ1 (NT1 * KT1 * 512)
#define SZ2 (NT2 * KI2 * 512)
#define SZ3 (NT3 * KI3 * 512)

__device__ inline float bf2f(ushort_t u) {
    union { uint_t i; float f; } x; x.i = ((uint_t)u) << 16; return x.f;
}
__device__ inline ushort_t f2bf(float f) {
    uint_t u = __float_as_uint(f);
    return (ushort_t)((u + 0x7FFFu + ((u >> 16) & 1u)) >> 16);
}
__device__ inline uint_t pack2(float a, float b) {
    return (uint_t)f2bf(a) | ((uint_t)f2bf(b) << 16);
}
__device__ inline float fast_tanh(float x) {
    float e = __expf(2.f * x);
    return 1.f - 2.f / (e + 1.f);
}
// async global->LDS, 16 B per lane; LDS dest = wave-uniform base + lane*16
__device__ inline void gl2lds16(const ushort_t* g, ushort_t* l) {
    __builtin_amdgcn_global_load_lds(
        (const __attribute__((address_space(1))) uint_t*)g,
        (__attribute__((address_space(3))) uint_t*)l, 16, 0, 0);
}

// ---------------------------------------------------------------------------
// pack_kernel: fp32 weights -> MFMA-tile-order bf16 + zero-padded fp32 biases.
//  W1t: 30 ntiles x 12 ktiles   (real n<400, k<376)
//  W2t: 20 ntiles x 13 ktiles   (real n<300, k<400)
//  Wht: 40 ntiles x 10 ktiles   (real n<559 per concat map, k<300)
//  head cols: [0:17) mu, [17:34) lv, [34:289) u, [289:544) w, [544:559) b
// ---------------------------------------------------------------------------
__global__ void pack_kernel(const float* __restrict__ W1, const float* __restrict__ W2,
                            const float* __restrict__ Wmu, const float* __restrict__ Wlv,
                            const float* __restrict__ Wu, const float* __restrict__ Ww,
                            const float* __restrict__ Wb,
                            const float* __restrict__ b1, const float* __restrict__ b2,
                            const float* __restrict__ bmu, const float* __restrict__ blv,
                            const float* __restrict__ bu, const float* __restrict__ bw,
                            const float* __restrict__ bb,
                            ushort_t* __restrict__ W1t, ushort_t* __restrict__ W2t,
                            ushort_t* __restrict__ Wht,
                            float* __restrict__ b1p, float* __restrict__ b2p,
                            float* __restrict__ bHp)
{
    int i = blockIdx.x * 256 + threadIdx.x;
    if (i < SZ1) {
        int t = i >> 9, pos = i & 511;
        int l = pos >> 3, j = pos & 7;
        int n = (t / KT1) * 16 + (l & 15);
        int k = (t % KT1) * 32 + (l >> 4) * 8 + j;
        W1t[i] = (n < 400 && k < 376) ? f2bf(W1[k * 400 + n]) : (ushort_t)0;
    } else if (i < SZ1 + SZ2) {
        int i2 = i - SZ1;
        int t = i2 >> 9, pos = i2 & 511;
        int l = pos >> 3, j = pos & 7;
        int n = (t / KI2) * 16 + (l & 15);
        int k = (t % KI2) * 32 + (l >> 4) * 8 + j;
        W2t[i2] = (n < 300 && k < 400) ? f2bf(W2[k * 300 + n]) : (ushort_t)0;
    } else if (i < SZ1 + SZ2 + SZ3) {
        int i3 = i - SZ1 - SZ2;
        int t = i3 >> 9, pos = i3 & 511;
        int l = pos >> 3, j = pos & 7;
        int n = (t / KI3) * 16 + (l & 15);
        int k = (t % KI3) * 32 + (l >> 4) * 8 + j;
        float v = 0.f;
        if (k < 300) {
            if      (n < 17)  v = Wmu[k * 17 + n];
            else if (n < 34)  v = Wlv[k * 17 + (n - 17)];
            else if (n < 289) v = Wu[k * 255 + (n - 34)];
            else if (n < 544) v = Ww[k * 255 + (n - 289)];
            else if (n < 559) v = Wb[k * 15 + (n - 544)];
        }
        Wht[i3] = f2bf(v);
    } else {
        int j = i - SZ1 - SZ2 - SZ3;
        if (j < 480) {
            b1p[j] = (j < 400) ? b1[j] : 0.f;
        } else if (j < 800) {
            int n = j - 480;
            b2p[n] = (n < 300) ? b2[n] : 0.f;
        } else if (j < 1440) {
            int n = j - 800;
            float v = 0.f;
            if      (n < 17)  v = bmu[n];
            else if (n < 34)  v = blv[n - 17];
            else if (n < 289) v = bu[n - 34];
            else if (n < 544) v = bw[n - 289];
            else if (n < 559) v = bb[n - 544];
            bHp[n] = v;
        }
    }
}

// ---------------------------------------------------------------------------
// cvt_kernel: x fp32 row-major -> x' bf16 tile-order. One thread per 16-B unit.
// ---------------------------------------------------------------------------
__global__ __launch_bounds__(256)
void cvt_kernel(const float* __restrict__ x, ushort_t* __restrict__ xt, int nUnits)
{
    int U = blockIdx.x * 256 + threadIdx.x;
    if (U >= nUnits) return;
    int t = U >> 6, l = U & 63;
    int rowblk = t / KT1, kblk = t - rowblk * KT1;
    long row = (long)rowblk * 16 + (l & 15);
    int k0 = kblk * 32 + (l >> 4) * 8;
    uint4 o = {0u, 0u, 0u, 0u};
    if (k0 + 8 <= 376) {
        const float4* p = reinterpret_cast<const float4*>(x + row * 376 + k0);
        float4 v0 = p[0], v1 = p[1];
        o.x = pack2(v0.x, v0.y); o.y = pack2(v0.z, v0.w);
        o.z = pack2(v1.x, v1.y); o.w = pack2(v1.z, v1.w);
    }
    reinterpret_cast<uint4*>(xt)[U] = o;   // unit order == linear 16-B order
}

// ---------------------------------------------------------------------------
// gemm_tile: C = act(A @ B^T + bias), all operands in MFMA-tile order except
// optionally C (row-major if !OUT_TILED).
// BM=128 (8 rowtiles), BN=160 (10 ntiles), BK=32; 256 thr = 4 waves.
// ---------------------------------------------------------------------------
template<bool RELU, bool OUT_TILED>
__global__ __launch_bounds__(256)
void gemm_tile(const ushort_t* __restrict__ A, const ushort_t* __restrict__ Bt,
               const float* __restrict__ bias, ushort_t* __restrict__ C,
               int kTA, int kIters, int kTC)
{
    __shared__ ushort_t As[8 * 512];
    __shared__ ushort_t Bs[10 * 512];
    const int tid = threadIdx.x;
    const int lane = tid & 63, wv = tid >> 6;
    const int q = lane >> 4, l16 = lane & 15;
    const int nb0 = blockIdx.x * 10;
    const int rowblk0 = blockIdx.y * 8;

    f32x4 acc[2][10];
    #pragma unroll
    for (int r = 0; r < 2; ++r)
        #pragma unroll
        for (int c = 0; c < 10; ++c)
            acc[r][c] = (f32x4){0.f, 0.f, 0.f, 0.f};

    for (int kt = 0; kt < kIters; ++kt) {
        // stage A: wave wv -> rowtiles 2wv, 2wv+1 (1024 B each, lds dest contiguous)
        #pragma unroll
        for (int i = 0; i < 2; ++i) {
            int t = wv * 2 + i;
            gl2lds16(A + (((size_t)(rowblk0 + t) * kTA + kt) << 9) + lane * 8,
                     &As[t << 9]);
        }
        // stage B: wave wv -> ntiles wv, wv+4, wv+8 (<10)
        #pragma unroll
        for (int t2 = 0; t2 < 3; ++t2) {
            int t = wv + t2 * 4;
            if (t < 10)
                gl2lds16(Bt + (((size_t)(nb0 + t) * kIters + kt) << 9) + lane * 8,
                         &Bs[t << 9]);
        }
        __syncthreads();

        bf16x8 a0 = __builtin_bit_cast(bf16x8,
            *reinterpret_cast<const uint4*>(&As[((wv * 2 + 0) << 9) + lane * 8]));
        bf16x8 a1 = __builtin_bit_cast(bf16x8,
            *reinterpret_cast<const uint4*>(&As[((wv * 2 + 1) << 9) + lane * 8]));
        #pragma unroll
        for (int c = 0; c < 10; ++c) {
            bf16x8 b = __builtin_bit_cast(bf16x8,
                *reinterpret_cast<const uint4*>(&Bs[(c << 9) + lane * 8]));
            acc[0][c] = __builtin_amdgcn_mfma_f32_16x16x32_bf16(a0, b, acc[0][c], 0, 0, 0);
            acc[1][c] = __builtin_amdgcn_mfma_f32_16x16x32_bf16(a1, b, acc[1][c], 0, 0, 0);
        }
        __syncthreads();
    }

    // epilogue: bias + act; C/D frag: col = l16, row = q*4+reg
    #pragma unroll
    for (int r = 0; r < 2; ++r) {
        int rowblk = rowblk0 + wv * 2 + r;
        #pragma unroll
        for (int c = 0; c < 10; ++c) {
            int n = (nb0 + c) * 16 + l16;
            float bv = bias[n];
            #pragma unroll
            for (int reg = 0; reg < 4; ++reg) {
                float v = acc[r][c][reg] + bv;
                if (RELU) v = fmaxf(v, 0.f);
                int mrow = q * 4 + reg;
                if (OUT_TILED) {
                    size_t off = (((size_t)rowblk * kTC + (n >> 5)) << 9)
                               + (size_t)(((n >> 3) & 3) * 16 + mrow) * 8 + (n & 7);
                    C[off] = f2bf(v);
                } else {
                    long m = (long)rowblk * 16 + mrow;
                    C[m * (long)kTC + n] = f2bf(v);
                }
            }
        }
    }
}

// ---------------------------------------------------------------------------
// flow_kernel v2: heads in MFMA-tile order (LDH3 ktiles/rowblock). One thread
// per row; NO LDS, NO barriers. In tile order, 8 consecutive n of one row are
// 16 contiguous, 16-B-aligned bytes:
//   off = (rowblk*LDH3 + (n>>5))*512 + ((n>>3)&3)*128 + (row&15)*8 + (n&7)
// The k-loop is fully unrolled -> all group indices/extract offsets are
// compile-time constants -> pure-register, deep load pipelining by compiler.
// 16 lanes of a wave read 256 B contiguous per group -> fully coalesced.
// ---------------------------------------------------------------------------
__device__ inline void ld_group8(const ushort_t* hb, int g, float* dst) {
    // g and dst indices must be compile-time constants at each call site.
    uint4 v = *reinterpret_cast<const uint4*>(hb + ((g >> 2) << 9) + ((g & 3) << 7));
    uint_t q[4] = {v.x, v.y, v.z, v.w};
    #pragma unroll
    for (int m = 0; m < 4; ++m) {
        dst[2 * m]     = __uint_as_float(q[m] << 16);          // low bf16
        dst[2 * m + 1] = __uint_as_float(q[m] & 0xFFFF0000u);  // high bf16
    }
}

__global__ __launch_bounds__(64)
void flow_kernel(const ushort_t* __restrict__ heads, const float* __restrict__ eps,
                 float* __restrict__ out, int rowBase, int Btot)
{
    const int tid = threadIdx.x;
    const long row = (long)blockIdx.x * 64 + tid;           // chunk-local row
    const ushort_t* hb = heads + (((size_t)(row >> 4) * LDH3) << 9)
                               + (size_t)((row & 15) << 3);

    // ---- init: mu (n 0..16), lv (n 17..33) -> groups 0..4 ----
    float z[17];
    float lp = 0.f;
    {
        float a[40];
        #pragma unroll
        for (int g = 0; g < 5; ++g) ld_group8(hb, g, &a[g * 8]);
        #pragma unroll
        for (int i = 0; i < 17; ++i) {
            float mu = fast_tanh(a[i]);
            float lv = fast_tanh(a[17 + i]);
            float ep = eps[row * 17 + i];
            z[i] = mu + __expf(lv) * ep;
            lp += -0.5f * ep * ep - lv - 0.918938533f;
        }
    }

    // ---- b_k (n 544..558) -> groups 68,69, loaded once ----
    float bv[16];
    ld_group8(hb, 68, &bv[0]);
    ld_group8(hb, 69, &bv[8]);

    // ---- planar-flow chain, fully unrolled over k ----
    float ldj = 0.f;
    #pragma unroll
    for (int k = 0; k < 15; ++k) {
        const int su = 34 + 17 * k;        // u_k start col
        const int sw = 289 + 17 * k;       // w_k start col
        const int gu = su >> 3, ou = su & 7;
        const int gw = sw >> 3, ow = sw & 7;
        float au[24], aw[24];
        ld_group8(hb, gu + 0, &au[0]);
        ld_group8(hb, gu + 1, &au[8]);
        ld_group8(hb, gu + 2, &au[16]);
        ld_group8(hb, gw + 0, &aw[0]);
        ld_group8(hb, gw + 1, &aw[8]);
        ld_group8(hb, gw + 2, &aw[16]);

        float uw = 0.f, w2 = 0.f, wz = 0.f;
        #pragma unroll
        for (int i = 0; i < 17; ++i) {
            float wi = aw[ow + i], ui = au[ou + i];
            uw += wi * ui;
            w2 += wi * wi;
            wz += wi * z[i];
        }
        float sp = (uw > 15.f) ? uw : __logf(1.f + __expf(uw));
        float m = sp - 1.f;                          // -1 + softplus(w.u)
        float coef = (m - uw) / fmaxf(w2, 1e-20f);
        float t = fast_tanh(wz + bv[k]);
        #pragma unroll
        for (int i = 0; i < 17; ++i)
            z[i] += (au[ou + i] + coef * aw[ow + i]) * t;
        float psi = m * (1.f - t * t);               // psi^T u_hat == m analytically
        ldj += __logf(fmaxf(fabsf(1.f + psi), 1e-30f));
    }

    const long g = rowBase + row;
    #pragma unroll
    for (int i = 0; i < 17; ++i) out[g * 17 + i] = z[i];
    float lpf = lp - ldj;
    out[(long)Btot * 17 + g] = __expf(lpf);
    out[(long)Btot * 18 + g] = lpf;
}

// ---------------------------------------------------------------------------
extern "C" void kernel_launch(void* const* d_in, const int* in_sizes, int n_in,
                              void* d_out, int out_size, void* d_ws, size_t ws_size,
                              hipStream_t stream)
{
    const float* x   = (const float*)d_in[0];
    const float* eps = (const float*)d_in[1];
    float* out = (float*)d_out;

    // ws layout per chunk of Mc rows:
    //   region1 (Mc*640 us): h1' tiled (uses Mc*480), later heads' tiled (Mc*640)
    //   region2 (Mc*384 us): x' tiled (Mc*384), later h2' tiled (Mc*320)
    //   weights: W1t | W2t | Wht | b1p(480 f32) | b2p(320) | bHp(640)
    const size_t wUS = (size_t)SZ1 + SZ2 + SZ3;
    const size_t fixedBytes = wUS * 2 + (480 + 320 + 640) * 4;
    int Mc = 2048;
    {
        const int cand[6] = {65536, 32768, 16384, 8192, 4096, 2048};
        for (int i = 0; i < 6; ++i) {
            size_t req = (size_t)cand[i] * 2048 + fixedBytes;
            if (req <= ws_size) { Mc = cand[i]; break; }
        }
    }

    ushort_t* region1 = (ushort_t*)d_ws;
    ushort_t* region2 = region1 + (size_t)Mc * 640;
    ushort_t* W1t = region2 + (size_t)Mc * 384;
    ushort_t* W2t = W1t + SZ1;
    ushort_t* Wht = W2t + SZ2;
    float* b1p = (float*)(Wht + SZ3);
    float* b2p = b1p + 480;
    float* bHp = b2p + 320;

    const int packN = SZ1 + SZ2 + SZ3 + 1440;
    pack_kernel<<<(packN + 255) / 256, 256, 0, stream>>>(
        (const float*)d_in[2],  (const float*)d_in[4],
        (const float*)d_in[6],  (const float*)d_in[8],
        (const float*)d_in[10], (const float*)d_in[12], (const float*)d_in[14],
        (const float*)d_in[3],  (const float*)d_in[5],
        (const float*)d_in[7],  (const float*)d_in[9],
        (const float*)d_in[11], (const float*)d_in[13], (const float*)d_in[15],
        W1t, W2t, Wht, b1p, b2p, bHp);

    const int nChunks = B_ROWS / Mc;
    const int nUnits = Mc * 48;                     // (Mc/16)*KT1*64
    for (int c = 0; c < nChunks; ++c) {
        const float* xc = x + (size_t)c * Mc * 376;
        // C0: x -> x' (bf16, tile order) in region2
        cvt_kernel<<<(nUnits + 255) / 256, 256, 0, stream>>>(xc, region2, nUnits);
        // K1: h1' = relu(x' @ W1^T + b1)   M=Mc K=384 N=480(pad) -> tiled, stride 15
        gemm_tile<true, true><<<dim3(3, Mc / 128), 256, 0, stream>>>(
            region2, W1t, b1p, region1, KT1, KT1, KTC1);
        // K2: h2' = relu(h1' @ W2^T + b2)  M=Mc K=416 N=320 -> tiled, stride 10
        gemm_tile<true, true><<<dim3(2, Mc / 128), 256, 0, stream>>>(
            region1, W2t, b2p, region2, KTC1, KI2, KTC2);
        // K3: heads' = h2' @ Wh^T + bH     M=Mc K=320 N=640(pad) -> TILED, stride 20
        gemm_tile<false, true><<<dim3(4, Mc / 128), 256, 0, stream>>>(
            region2, Wht, bHp, region1, KTC2, KI3, LDH3);
        // K4: planar flow + log-prob (LDS-free, reads tiled heads)
        flow_kernel<<<Mc / 64, 64, 0, stream>>>(region1, eps + (size_t)c * Mc * 17,
                                                out, c * Mc, B_ROWS);
    }
}

// Round 2
// 366.528 us; speedup vs baseline: 1.0401x; 1.0401x over previous
//
#include <hip/hip_runtime.h>

typedef unsigned short ushort_t;
typedef unsigned int uint_t;
typedef __bf16 bf16x8 __attribute__((ext_vector_type(8)));
typedef float f32x4 __attribute__((ext_vector_type(4)));

#define B_ROWS 65536

// Tile geometry: one MFMA tile = 16 rows x 32 k of bf16 = 1024 B = 512 ushorts.
// Unit l (0..63) within a tile <-> (row = l&15, k = (l>>4)*8 .. +8).
#define KT1 12    // x' k-tiles   (K 376 -> 384)
#define NT1 30    // K1 n-tiles   (N 400 -> 480)
#define KTC1 15   // h1' k-tiles  (480/32)
#define KI2 13    // K2 k-iters   (K 400 -> 416)
#define NT2 20    // K2 n-tiles   (N 320)
#define KTC2 10   // h2' k-tiles  (320/32)
#define KI3 10    // K3 k-iters   (320/32)
#define NT3 50    // K3 n-tiles   (N 800: aligned head layout)
#define LDH3 25   // heads' row-stride in ktiles (800/32)

// Aligned head layout (all slots on 8-col boundaries; pads are exact zeros):
//  [0:24)  mu (17 real)   groups 0..2
//  [24:48) lv (17 real)   groups 3..5
//  [48:64) b  (15 real)   groups 6..7
//  [64+48k : 64+48k+24)  u_k (17 real)  groups 8+6k .. +2
//  [64+48k+24 : +48)     w_k (17 real)  groups 11+6k .. +2

#define SZ1 (NT1 * KT1 * 512)
#define SZ2 (NT2 * KI2 * 512)
#define SZ3 (NT3 * KI3 * 512)

__device__ inline float bf2f(ushort_t u) {
    union { uint_t i; float f; } x; x.i = ((uint_t)u) << 16; return x.f;
}
__device__ inline ushort_t f2bf(float f) {
    uint_t u = __float_as_uint(f);
    return (ushort_t)((u + 0x7FFFu + ((u >> 16) & 1u)) >> 16);
}
__device__ inline uint_t pack2(float a, float b) {
    return (uint_t)f2bf(a) | ((uint_t)f2bf(b) << 16);
}
__device__ inline float fast_tanh(float x) {
    float e = __expf(2.f * x);
    return 1.f - 2.f / (e + 1.f);
}
// async global->LDS, 16 B per lane; LDS dest = wave-uniform base + lane*16
__device__ inline void gl2lds16(const ushort_t* g, ushort_t* l) {
    __builtin_amdgcn_global_load_lds(
        (const __attribute__((address_space(1))) uint_t*)g,
        (__attribute__((address_space(3))) uint_t*)l, 16, 0, 0);
}

// ---------------------------------------------------------------------------
// pack_kernel: fp32 weights -> MFMA-tile-order bf16 + zero-padded fp32 biases.
// ---------------------------------------------------------------------------
__global__ void pack_kernel(const float* __restrict__ W1, const float* __restrict__ W2,
                            const float* __restrict__ Wmu, const float* __restrict__ Wlv,
                            const float* __restrict__ Wu, const float* __restrict__ Ww,
                            const float* __restrict__ Wb,
                            const float* __restrict__ b1, const float* __restrict__ b2,
                            const float* __restrict__ bmu, const float* __restrict__ blv,
                            const float* __restrict__ bu, const float* __restrict__ bw,
                            const float* __restrict__ bb,
                            ushort_t* __restrict__ W1t, ushort_t* __restrict__ W2t,
                            ushort_t* __restrict__ Wht,
                            float* __restrict__ b1p, float* __restrict__ b2p,
                            float* __restrict__ bHp)
{
    int i = blockIdx.x * 256 + threadIdx.x;
    if (i < SZ1) {
        int t = i >> 9, pos = i & 511;
        int l = pos >> 3, j = pos & 7;
        int n = (t / KT1) * 16 + (l & 15);
        int k = (t % KT1) * 32 + (l >> 4) * 8 + j;
        W1t[i] = (n < 400 && k < 376) ? f2bf(W1[k * 400 + n]) : (ushort_t)0;
    } else if (i < SZ1 + SZ2) {
        int i2 = i - SZ1;
        int t = i2 >> 9, pos = i2 & 511;
        int l = pos >> 3, j = pos & 7;
        int n = (t / KI2) * 16 + (l & 15);
        int k = (t % KI2) * 32 + (l >> 4) * 8 + j;
        W2t[i2] = (n < 300 && k < 400) ? f2bf(W2[k * 300 + n]) : (ushort_t)0;
    } else if (i < SZ1 + SZ2 + SZ3) {
        int i3 = i - SZ1 - SZ2;
        int t = i3 >> 9, pos = i3 & 511;
        int l = pos >> 3, j = pos & 7;
        int n = (t / KI3) * 16 + (l & 15);
        int k = (t % KI3) * 32 + (l >> 4) * 8 + j;
        float v = 0.f;
        if (k < 300) {
            if (n < 24)      { if (n < 17) v = Wmu[k * 17 + n]; }
            else if (n < 48) { int c = n - 24; if (c < 17) v = Wlv[k * 17 + c]; }
            else if (n < 64) { int c = n - 48; if (c < 15) v = Wb[k * 15 + c]; }
            else if (n < 784) {
                int r = n - 64, slot = r / 48, c = r % 48;
                if (c < 24) { if (c < 17) v = Wu[k * 255 + slot * 17 + c]; }
                else        { int c2 = c - 24; if (c2 < 17) v = Ww[k * 255 + slot * 17 + c2]; }
            }
        }
        Wht[i3] = f2bf(v);
    } else {
        int j = i - SZ1 - SZ2 - SZ3;
        if (j < 480) {
            b1p[j] = (j < 400) ? b1[j] : 0.f;
        } else if (j < 800) {
            int n = j - 480;
            b2p[n] = (n < 300) ? b2[n] : 0.f;
        } else if (j < 1600) {
            int n = j - 800;
            float v = 0.f;
            if (n < 24)      { if (n < 17) v = bmu[n]; }
            else if (n < 48) { int c = n - 24; if (c < 17) v = blv[c]; }
            else if (n < 64) { int c = n - 48; if (c < 15) v = bb[c]; }
            else if (n < 784) {
                int r = n - 64, slot = r / 48, c = r % 48;
                if (c < 24) { if (c < 17) v = bu[slot * 17 + c]; }
                else        { int c2 = c - 24; if (c2 < 17) v = bw[slot * 17 + c2]; }
            }
            bHp[n] = v;
        }
    }
}

// ---------------------------------------------------------------------------
// cvt_kernel: x fp32 row-major -> x' bf16 tile-order. One thread per 16-B unit.
// ---------------------------------------------------------------------------
__global__ __launch_bounds__(256)
void cvt_kernel(const float* __restrict__ x, ushort_t* __restrict__ xt, int nUnits)
{
    int U = blockIdx.x * 256 + threadIdx.x;
    if (U >= nUnits) return;
    int t = U >> 6, l = U & 63;
    int rowblk = t / KT1, kblk = t - rowblk * KT1;
    long row = (long)rowblk * 16 + (l & 15);
    int k0 = kblk * 32 + (l >> 4) * 8;
    uint4 o = {0u, 0u, 0u, 0u};
    if (k0 + 8 <= 376) {
        const float4* p = reinterpret_cast<const float4*>(x + row * 376 + k0);
        float4 v0 = p[0], v1 = p[1];
        o.x = pack2(v0.x, v0.y); o.y = pack2(v0.z, v0.w);
        o.z = pack2(v1.x, v1.y); o.w = pack2(v1.z, v1.w);
    }
    reinterpret_cast<uint4*>(xt)[U] = o;   // unit order == linear 16-B order
}

// ---------------------------------------------------------------------------
// gemm_tile: C = act(A @ B^T + bias), operands in MFMA-tile order.
// BM=128 (8 rowtiles), BN=160 (10 ntiles), BK=32; 256 thr = 4 waves.
// ---------------------------------------------------------------------------
template<bool RELU, bool OUT_TILED>
__global__ __launch_bounds__(256)
void gemm_tile(const ushort_t* __restrict__ A, const ushort_t* __restrict__ Bt,
               const float* __restrict__ bias, ushort_t* __restrict__ C,
               int kTA, int kIters, int kTC)
{
    __shared__ ushort_t As[8 * 512];
    __shared__ ushort_t Bs[10 * 512];
    const int tid = threadIdx.x;
    const int lane = tid & 63, wv = tid >> 6;
    const int q = lane >> 4, l16 = lane & 15;
    const int nb0 = blockIdx.x * 10;
    const int rowblk0 = blockIdx.y * 8;

    f32x4 acc[2][10];
    #pragma unroll
    for (int r = 0; r < 2; ++r)
        #pragma unroll
        for (int c = 0; c < 10; ++c)
            acc[r][c] = (f32x4){0.f, 0.f, 0.f, 0.f};

    for (int kt = 0; kt < kIters; ++kt) {
        #pragma unroll
        for (int i = 0; i < 2; ++i) {
            int t = wv * 2 + i;
            gl2lds16(A + (((size_t)(rowblk0 + t) * kTA + kt) << 9) + lane * 8,
                     &As[t << 9]);
        }
        #pragma unroll
        for (int t2 = 0; t2 < 3; ++t2) {
            int t = wv + t2 * 4;
            if (t < 10)
                gl2lds16(Bt + (((size_t)(nb0 + t) * kIters + kt) << 9) + lane * 8,
                         &Bs[t << 9]);
        }
        __syncthreads();

        bf16x8 a0 = __builtin_bit_cast(bf16x8,
            *reinterpret_cast<const uint4*>(&As[((wv * 2 + 0) << 9) + lane * 8]));
        bf16x8 a1 = __builtin_bit_cast(bf16x8,
            *reinterpret_cast<const uint4*>(&As[((wv * 2 + 1) << 9) + lane * 8]));
        #pragma unroll
        for (int c = 0; c < 10; ++c) {
            bf16x8 b = __builtin_bit_cast(bf16x8,
                *reinterpret_cast<const uint4*>(&Bs[(c << 9) + lane * 8]));
            acc[0][c] = __builtin_amdgcn_mfma_f32_16x16x32_bf16(a0, b, acc[0][c], 0, 0, 0);
            acc[1][c] = __builtin_amdgcn_mfma_f32_16x16x32_bf16(a1, b, acc[1][c], 0, 0, 0);
        }
        __syncthreads();
    }

    // epilogue: bias + act; C/D frag: col = l16, row = q*4+reg
    #pragma unroll
    for (int r = 0; r < 2; ++r) {
        int rowblk = rowblk0 + wv * 2 + r;
        #pragma unroll
        for (int c = 0; c < 10; ++c) {
            int n = (nb0 + c) * 16 + l16;
            float bv = bias[n];
            #pragma unroll
            for (int reg = 0; reg < 4; ++reg) {
                float v = acc[r][c][reg] + bv;
                if (RELU) v = fmaxf(v, 0.f);
                int mrow = q * 4 + reg;
                if (OUT_TILED) {
                    size_t off = (((size_t)rowblk * kTC + (n >> 5)) << 9)
                               + (size_t)(((n >> 3) & 3) * 16 + mrow) * 8 + (n & 7);
                    C[off] = f2bf(v);
                } else {
                    long m = (long)rowblk * 16 + mrow;
                    C[m * (long)kTC + n] = f2bf(v);
                }
            }
        }
    }
}

// ---------------------------------------------------------------------------
// flow_kernel v3: 4 lanes per row (lane sub owns head cols [8*sub, 8*sub+8)).
// Aligned 48-col u/w slots -> each lane reads ONE uint4 per vector, fully
// coalesced (wave = 16 rows x 3 groups = 768 contiguous bytes per operand).
// Dots reduced across the 4-lane group via shfl_xor(1,2). No LDS, no spills:
// per-lane live state ~50 floats. 65536 rows x 4 lanes = 4096 waves = 4/SIMD.
//   group g byte offset within rowblock: (g>>2)*1024 + (g&3)*256 + (row&15)*16
// ---------------------------------------------------------------------------
__device__ inline void ld_group8(const ushort_t* hb, int g, float* dst) {
    uint4 v = *reinterpret_cast<const uint4*>(hb + ((g >> 2) << 9) + ((g & 3) << 7));
    uint_t q[4] = {v.x, v.y, v.z, v.w};
    #pragma unroll
    for (int m = 0; m < 4; ++m) {
        dst[2 * m]     = __uint_as_float(q[m] << 16);          // low bf16
        dst[2 * m + 1] = __uint_as_float(q[m] & 0xFFFF0000u);  // high bf16
    }
}

__global__ __launch_bounds__(256, 4)
void flow_kernel(const ushort_t* __restrict__ heads, const float* __restrict__ eps,
                 float* __restrict__ out, int rowBase, int Btot)
{
    const int tid = threadIdx.x;
    const int sub = tid & 3;
    const long row = (long)blockIdx.x * 64 + (tid >> 2);
    const ushort_t* hb = heads + (((size_t)(row >> 4) * LDH3) << 9)
                               + (size_t)((row & 15) << 3);

    // ---- init: mu (groups 0..2), lv (groups 3..5) ----
    float z[8];
    float lp = 0.f;
    {
        float amu[8] = {0,0,0,0,0,0,0,0}, alv[8] = {0,0,0,0,0,0,0,0};
        if (sub < 3) {
            ld_group8(hb, sub, amu);
            ld_group8(hb, 3 + sub, alv);
        }
        float ep[8];
        #pragma unroll
        for (int c = 0; c < 8; ++c) {
            int i = sub * 8 + c;
            ep[c] = (i < 17) ? eps[row * 17 + i] : 0.f;
        }
        #pragma unroll
        for (int c = 0; c < 8; ++c) {
            float mu = fast_tanh(amu[c]);
            float lv = fast_tanh(alv[c]);
            z[c] = mu + __expf(lv) * ep[c];
            int i = sub * 8 + c;
            lp += (i < 17) ? (-0.5f * ep[c] * ep[c] - lv - 0.918938533f) : 0.f;
        }
    }

    // ---- b (groups 6,7), loaded once per lane ----
    float bv[16];
    ld_group8(hb, 6, &bv[0]);
    ld_group8(hb, 7, &bv[8]);

    // ---- planar-flow chain, fully unrolled over k ----
    float ldj = 0.f;
    #pragma unroll
    for (int k = 0; k < 15; ++k) {
        float au[8] = {0,0,0,0,0,0,0,0}, aw[8] = {0,0,0,0,0,0,0,0};
        if (sub < 3) {
            ld_group8(hb, 8 + 6 * k + sub, au);
            ld_group8(hb, 11 + 6 * k + sub, aw);
        }
        float uw = 0.f, w2 = 0.f, wz = 0.f;
        #pragma unroll
        for (int c = 0; c < 8; ++c) {
            uw += aw[c] * au[c];
            w2 += aw[c] * aw[c];
            wz += aw[c] * z[c];
        }
        uw += __shfl_xor(uw, 1); uw += __shfl_xor(uw, 2);
        w2 += __shfl_xor(w2, 1); w2 += __shfl_xor(w2, 2);
        wz += __shfl_xor(wz, 1); wz += __shfl_xor(wz, 2);

        float sp = (uw > 15.f) ? uw : __logf(1.f + __expf(uw));
        float m = sp - 1.f;                          // -1 + softplus(w.u)
        float coef = (m - uw) / fmaxf(w2, 1e-20f);
        float t = fast_tanh(wz + bv[k]);
        #pragma unroll
        for (int c = 0; c < 8; ++c)
            z[c] += (au[c] + coef * aw[c]) * t;
        float psi = m * (1.f - t * t);               // psi^T u_hat == m analytically
        ldj += __logf(fmaxf(fabsf(1.f + psi), 1e-30f));
    }

    lp += __shfl_xor(lp, 1); lp += __shfl_xor(lp, 2);
    const long g = rowBase + row;
    #pragma unroll
    for (int c = 0; c < 8; ++c) {
        int i = sub * 8 + c;
        if (i < 17) out[g * 17 + i] = z[c];
    }
    float lpf = lp - ldj;
    if (sub == 0) {
        out[(long)Btot * 17 + g] = __expf(lpf);
        out[(long)Btot * 18 + g] = lpf;
    }
}

// ---------------------------------------------------------------------------
extern "C" void kernel_launch(void* const* d_in, const int* in_sizes, int n_in,
                              void* d_out, int out_size, void* d_ws, size_t ws_size,
                              hipStream_t stream)
{
    const float* x   = (const float*)d_in[0];
    const float* eps = (const float*)d_in[1];
    float* out = (float*)d_out;

    // ws layout per chunk of Mc rows:
    //   region1 (Mc*800 us): h1' tiled (uses Mc*480), later heads' tiled (Mc*800)
    //   region2 (Mc*384 us): x' tiled (Mc*384), later h2' tiled (Mc*320)
    //   weights: W1t | W2t | Wht | b1p(480 f32) | b2p(320) | bHp(800)
    const size_t wUS = (size_t)SZ1 + SZ2 + SZ3;
    const size_t fixedBytes = wUS * 2 + (480 + 320 + 800) * 4;
    int Mc = 2048;
    {
        const int cand[6] = {65536, 32768, 16384, 8192, 4096, 2048};
        for (int i = 0; i < 6; ++i) {
            size_t req = (size_t)cand[i] * 2368 + fixedBytes;
            if (req <= ws_size) { Mc = cand[i]; break; }
        }
    }

    ushort_t* region1 = (ushort_t*)d_ws;
    ushort_t* region2 = region1 + (size_t)Mc * 800;
    ushort_t* W1t = region2 + (size_t)Mc * 384;
    ushort_t* W2t = W1t + SZ1;
    ushort_t* Wht = W2t + SZ2;
    float* b1p = (float*)(Wht + SZ3);
    float* b2p = b1p + 480;
    float* bHp = b2p + 320;

    const int packN = SZ1 + SZ2 + SZ3 + 1600;
    pack_kernel<<<(packN + 255) / 256, 256, 0, stream>>>(
        (const float*)d_in[2],  (const float*)d_in[4],
        (const float*)d_in[6],  (const float*)d_in[8],
        (const float*)d_in[10], (const float*)d_in[12], (const float*)d_in[14],
        (const float*)d_in[3],  (const float*)d_in[5],
        (const float*)d_in[7],  (const float*)d_in[9],
        (const float*)d_in[11], (const float*)d_in[13], (const float*)d_in[15],
        W1t, W2t, Wht, b1p, b2p, bHp);

    const int nChunks = B_ROWS / Mc;
    const int nUnits = Mc * 48;                     // (Mc/16)*KT1*64
    for (int c = 0; c < nChunks; ++c) {
        const float* xc = x + (size_t)c * Mc * 376;
        // C0: x -> x' (bf16, tile order) in region2
        cvt_kernel<<<(nUnits + 255) / 256, 256, 0, stream>>>(xc, region2, nUnits);
        // K1: h1' = relu(x' @ W1^T + b1)   M=Mc K=384 N=480(pad) -> tiled, stride 15
        gemm_tile<true, true><<<dim3(3, Mc / 128), 256, 0, stream>>>(
            region2, W1t, b1p, region1, KT1, KT1, KTC1);
        // K2: h2' = relu(h1' @ W2^T + b2)  M=Mc K=416 N=320 -> tiled, stride 10
        gemm_tile<true, true><<<dim3(2, Mc / 128), 256, 0, stream>>>(
            region1, W2t, b2p, region2, KTC1, KI2, KTC2);
        // K3: heads' = h2' @ Wh^T + bH     M=Mc K=320 N=800(pad) -> tiled, stride 25
        gemm_tile<false, true><<<dim3(5, Mc / 128), 256, 0, stream>>>(
            region2, Wht, bHp, region1, KTC2, KI3, LDH3);
        // K4: planar flow + log-prob (4 lanes/row, aligned slots, no LDS)
        flow_kernel<<<Mc / 64, 256, 0, stream>>>(region1, eps + (size_t)c * Mc * 17,
                                                 out, c * Mc, B_ROWS);
    }
}